// Round 15
// baseline (73.862 us; speedup 1.0000x reference)
//
#include <hip/hip_runtime.h>
#include <hip/hip_fp16.h>

// DCNv2: B=2, CIN=COUT=64, H=W=128, DG=8, cpg=8, 3x3 s1 p1 d1
constexpr int BB = 2;
constexpr int CINc = 64;
constexpr int HWc = 128 * 128;
constexpr int OCOFFc = 216;   // DG*3*9 offset-conv channels
constexpr int XP = 130;       // padded spatial dim (halo of 1)

// workspace layout (bytes)
constexpr size_t XT_BYTES  = (size_t)BB * 8 * XP * XP * 8 * 2;   // per-(b,dg) planes, 16B/px
constexpr size_t WB1_OFF   = XT_BYTES;
constexpr size_t WB1_BYTES = (size_t)9 * 8 * 256 * 8 * 2;        // offset W [tap][cgrp][oc256][8ci] fp16
constexpr size_t WM_OFF    = WB1_OFF + WB1_BYTES;
constexpr size_t WM_BYTES  = (size_t)8 * 12 * 64 * 8 * 2;        // main W [dg][tap12][oc][8c] fp16
constexpr size_t OFFST_OFF = WM_OFF + WM_BYTES;
constexpr size_t OFFST_BYTES = (size_t)BB * 128 * 216 * 128 * 2; // diag offsT [b][blk128][216][128px]
constexpr size_t WS_NEEDED = OFFST_OFF + OFFST_BYTES;            // ~18.9 MB

typedef _Float16 f16x8 __attribute__((ext_vector_type(8)));
typedef float    f32x4 __attribute__((ext_vector_type(4)));

// ---------- K0: fused prep: x->planes, weight transforms, halo zero ----------
__global__ void prep_all(const float* __restrict__ x, const float* __restrict__ w_off,
                         const float* __restrict__ weight,
                         __half* __restrict__ xT, __half* __restrict__ wB1,
                         __half* __restrict__ wM) {
    int bid = blockIdx.x;
    if (bid < 1024) {
        int site = bid * 256 + threadIdx.x;      // B*8*HW = 262144
        int pix = site & (HWc - 1);
        int bdg = site >> 14;
        int dg = bdg & 7, b = bdg >> 3;
        int y = pix >> 7, xc = pix & 127;
        const float* xp = x + (size_t)(b * CINc + dg * 8) * HWc + pix;
        __half2 h0 = __halves2half2(__float2half(xp[0 * HWc]), __float2half(xp[1 * HWc]));
        __half2 h1 = __halves2half2(__float2half(xp[2 * HWc]), __float2half(xp[3 * HWc]));
        __half2 h2 = __halves2half2(__float2half(xp[4 * HWc]), __float2half(xp[5 * HWc]));
        __half2 h3 = __halves2half2(__float2half(xp[6 * HWc]), __float2half(xp[7 * HWc]));
        __half2* o = reinterpret_cast<__half2*>(
            xT + (((size_t)(b * 8 + dg) * XP + y + 1) * XP + xc + 1) * 8);
        o[0] = h0; o[1] = h1; o[2] = h2; o[3] = h3;
        return;
    }
    int idx = (bid - 1024) * 256 + threadIdx.x;
    if (idx < 9 * 8 * 256 * 8) {
        // wB1[tap][cgrp][oc][ci]: fragment-major, coalesced for direct global B-reads
        int ci = idx & 7;
        int oc = (idx >> 3) & 255;
        int c  = (idx >> 11) & 7;
        int tap = idx >> 14;
        float v = (oc < OCOFFc) ? w_off[oc * 576 + (c * 8 + ci) * 9 + tap] : 0.f;
        wB1[idx] = __float2half(v);
    } else if (idx < 9 * 8 * 256 * 8 + 8 * 12 * 64 * 8) {
        int j = idx - 9 * 8 * 256 * 8;       // wM[dg][tap12][oc][c]
        int c = j & 7;
        int oc = (j >> 3) & 63;
        int tg = j >> 9;                      // dg*12 + tap
        int tap = tg % 12;
        int dg = tg / 12;
        float v = (tap < 9) ? weight[oc * 576 + (dg * 8 + c) * 9 + tap] : 0.f;
        wM[j] = __float2half(v);
    } else {
        int j2 = idx - (9 * 8 * 256 * 8 + 8 * 12 * 64 * 8);   // halo zero: 16 planes x 516 px
        if (j2 < 16 * 516) {
            int plane = j2 / 516;
            int p = j2 - plane * 516;
            int y, xx;
            if (p < 130)      { y = 0;           xx = p; }
            else if (p < 260) { y = 129;         xx = p - 130; }
            else if (p < 388) { y = 1 + p - 260; xx = 0; }
            else              { y = 1 + p - 388; xx = 129; }
            uint4 z = {0u, 0u, 0u, 0u};
            *reinterpret_cast<uint4*>(xT + (((size_t)plane * XP + y) * XP + xx) * 8) = z;
        }
    }
}

// Phase B: issue all 12 corner gathers + blend weights for group DG into regs
#define DCN_ISSUE(DG, G, W)                                                    \
  {                                                                            \
    const int dg_ = (DG);                                                      \
    const __half* xb_ = xT + (size_t)(b * 8 + dg_) * XP * XP * 8;              \
    _Pragma("unroll")                                                          \
    for (int s_ = 0; s_ < 3; ++s_) {                                           \
      const int kg_ = s_ * 4 + lh;                                             \
      if (kg_ < 9) {                                                           \
        const int r3_ = (dg_ * 9 + kg_) * 3;                                   \
        float oy_ = __half2float(offsb[r3_ * 130 + px]);                       \
        float ox_ = __half2float(offsb[(r3_ + 1) * 130 + px]);                 \
        float mk_ = __half2float(offsb[(r3_ + 2) * 130 + px]);                 \
        const int ki_ = kg_ / 3, kj_ = kg_ - ki_ * 3;                          \
        float sy_ = oy_ + (float)(gy - 1 + ki_);                               \
        float sx_ = ox_ + (float)(gx - 1 + kj_);                               \
        float y0f_ = floorf(sy_), x0f_ = floorf(sx_);                          \
        int iy0_ = (int)y0f_, ix0_ = (int)x0f_;                                \
        float ly_ = sy_ - y0f_, lx_ = sx_ - x0f_;                              \
        float hy_ = 1.f - ly_, hx_ = 1.f - lx_;                                \
        float vy0_ = ((unsigned)iy0_ < 128u) ? 1.f : 0.f;                      \
        float vy1_ = ((unsigned)(iy0_ + 1) < 128u) ? 1.f : 0.f;                \
        float vx0_ = ((unsigned)ix0_ < 128u) ? 1.f : 0.f;                      \
        float vx1_ = ((unsigned)(ix0_ + 1) < 128u) ? 1.f : 0.f;                \
        W[s_ * 4 + 0] = hy_ * hx_ * vy0_ * vx0_ * mk_;                         \
        W[s_ * 4 + 1] = hy_ * lx_ * vy0_ * vx1_ * mk_;                         \
        W[s_ * 4 + 2] = ly_ * hx_ * vy1_ * vx0_ * mk_;                         \
        W[s_ * 4 + 3] = ly_ * lx_ * vy1_ * vx1_ * mk_;                         \
        int y0c_ = min(max(iy0_, 0), 127), y1c_ = min(max(iy0_ + 1, 0), 127);  \
        int x0c_ = min(max(ix0_, 0), 127), x1c_ = min(max(ix0_ + 1, 0), 127);  \
        G[s_ * 4 + 0] = *reinterpret_cast<const float4*>(xb_ + ((size_t)(y0c_ + 1) * XP + x0c_ + 1) * 8); \
        G[s_ * 4 + 1] = *reinterpret_cast<const float4*>(xb_ + ((size_t)(y0c_ + 1) * XP + x1c_ + 1) * 8); \
        G[s_ * 4 + 2] = *reinterpret_cast<const float4*>(xb_ + ((size_t)(y1c_ + 1) * XP + x0c_ + 1) * 8); \
        G[s_ * 4 + 3] = *reinterpret_cast<const float4*>(xb_ + ((size_t)(y1c_ + 1) * XP + x1c_ + 1) * 8); \
      } else {                                                                 \
        const float4 z4_ = {0.f, 0.f, 0.f, 0.f};                               \
        W[s_ * 4 + 0] = 0.f; W[s_ * 4 + 1] = 0.f;                              \
        W[s_ * 4 + 2] = 0.f; W[s_ * 4 + 3] = 0.f;                              \
        G[s_ * 4 + 0] = z4_; G[s_ * 4 + 1] = z4_;                              \
        G[s_ * 4 + 2] = z4_; G[s_ * 4 + 3] = z4_;                              \
      }                                                                        \
    }                                                                          \
  }

// Phase B: blend staged corners -> af fragments, then 12 MFMAs for group DG
#define DCN_CONSUME(DG, G, W)                                                  \
  {                                                                            \
    const int dg_ = (DG);                                                      \
    f16x8 bf_[12];                                                             \
    _Pragma("unroll")                                                          \
    for (int s_ = 0; s_ < 3; ++s_)                                             \
      _Pragma("unroll")                                                        \
      for (int n_ = 0; n_ < 4; ++n_)                                           \
        bf_[s_ * 4 + n_] = *reinterpret_cast<const f16x8*>(                    \
            wM + (size_t)((dg_ * 12 + s_ * 4 + lh) * 64 + n_ * 16 + l15) * 8); \
    f16x8 af_[3];                                                              \
    _Pragma("unroll")                                                          \
    for (int s_ = 0; s_ < 3; ++s_) {                                           \
      __half2 W00_ = __float2half2_rn(W[s_ * 4 + 0]);                          \
      __half2 W01_ = __float2half2_rn(W[s_ * 4 + 1]);                          \
      __half2 W10_ = __float2half2_rn(W[s_ * 4 + 2]);                          \
      __half2 W11_ = __float2half2_rn(W[s_ * 4 + 3]);                          \
      const __half2* a00_ = reinterpret_cast<const __half2*>(&G[s_ * 4 + 0]);  \
      const __half2* a01_ = reinterpret_cast<const __half2*>(&G[s_ * 4 + 1]);  \
      const __half2* a10_ = reinterpret_cast<const __half2*>(&G[s_ * 4 + 2]);  \
      const __half2* a11_ = reinterpret_cast<const __half2*>(&G[s_ * 4 + 3]);  \
      __align__(16) __half2 rr_[4];                                            \
      _Pragma("unroll")                                                        \
      for (int cc_ = 0; cc_ < 4; ++cc_)                                        \
        rr_[cc_] = __hfma2(a00_[cc_], W00_,                                    \
                   __hfma2(a01_[cc_], W01_,                                    \
                   __hfma2(a10_[cc_], W10_, __hmul2(a11_[cc_], W11_))));       \
      af_[s_] = *reinterpret_cast<const f16x8*>(rr_);                          \
    }                                                                          \
    _Pragma("unroll")                                                          \
    for (int s_ = 0; s_ < 3; ++s_)                                             \
      _Pragma("unroll")                                                        \
      for (int n_ = 0; n_ < 4; ++n_)                                           \
        acc2[n_] = __builtin_amdgcn_mfma_f32_16x16x32_f16(                     \
            af_[s_], bf_[s_ * 4 + n_], acc2[n_], 0, 0, 0);                     \
  }

// ---------- Fused DCN (r10 structure) with ablation phases ----------
// PHASE 0: full fused (offsb in LDS), writes d_out.
// PHASE 1: Phase A only, epilogue -> offsT (global ws). Diagnostic.
// PHASE 2: Phase B only, offsb staged from offsT; writes d_out (same values as 0).
template <int PHASE>
__global__ __launch_bounds__(512, 2) void dcn_fused_k(
        const __half* __restrict__ xT, const __half* __restrict__ wB1,
        const float* __restrict__ cob, const __half* __restrict__ wM,
        const float* __restrict__ bias, __half* __restrict__ offsT,
        float* __restrict__ out) {
    __shared__ __half xs[1440 * 8];       // 23040 B: [row10][col18][sl8][8ch]
    __shared__ __half offsb[216 * 130];   // 56160 B: [(dg*9+k)*3+comp][px128 pad130]
    const int tid = threadIdx.x;
    // keep LDS footprint identical across instantiations (comparable occupancy)
    if (offsT == nullptr) { xs[0] = __float2half(0.f); offsb[0] = __float2half(0.f); }
    // XCD-aware swizzle: each XCD gets 32 consecutive vids = 4 contiguous row-bands
    const int fid = blockIdx.x + (blockIdx.y << 3) + (blockIdx.z << 7);
    const int vid = ((fid & 7) << 5) + (fid >> 3);
    const int bx = vid & 7;               // 0..7   (16 px wide)
    const int by = (vid >> 3) & 15;       // 0..15  (8 px tall)
    const int b  = vid >> 7;
    const int blin = by * 8 + bx;         // 0..127
    __half* offsTb = offsT + ((size_t)(b * 128 + blin)) * 216 * 128;

    if constexpr (PHASE != 2) {
        // ---- Phase A staging: x patch rows by*8..+9, cols bx*16..+17, XOR swizzle ----
        #pragma unroll
        for (int it = 0; it < 3; ++it) {
            int idx = tid + it * 512;
            if (idx < 1440) {
                int yl = idx / 144;                  // 144 = 18 cols * 8 slots
                int rem = idx - yl * 144;
                int cl = rem >> 3, sl = rem & 7;
                int dg = sl ^ (cl & 7);
                float4 v = *reinterpret_cast<const float4*>(
                    xT + (((size_t)(b * 8 + dg) * XP + by * 8 + yl) * XP + bx * 16 + cl) * 8);
                *reinterpret_cast<float4*>(xs + idx * 8) = v;
            }
        }
    } else {
        // ---- PHASE 2: stage offsb from offsT (written by PHASE 1 dispatch) ----
        #pragma unroll 1
        for (int idx = tid; idx < 216 * 64; idx += 512) {
            int row = idx >> 6;            // 64 half2 per row of 128 px
            int c2 = idx & 63;
            *reinterpret_cast<__half2*>(&offsb[row * 130 + c2 * 2]) =
                *reinterpret_cast<const __half2*>(offsTb + row * 128 + c2 * 2);
        }
    }
    __syncthreads();   // barrier 1

    const int lane = tid & 63;
    const int wid = tid >> 6;
    const int l15 = lane & 15, lh = lane >> 4;

    if constexpr (PHASE != 2) {
        // ---- Phase A: 9-tap implicit GEMM, NO barriers; bf direct from global ----
        const int wr = wid & 1;            // px half (4 image rows)
        const int wc = wid >> 1;           // oc quarter (64 of 256)
        f32x4 acc[4][4];
        const f32x4 zero = {0.f, 0.f, 0.f, 0.f};
        #pragma unroll
        for (int ty = 0; ty < 4; ++ty)
            #pragma unroll
            for (int ot = 0; ot < 4; ++ot) acc[ty][ot] = zero;

        #pragma unroll 3
        for (int tap = 0; tap < 9; ++tap) {
            const int r = tap / 3, s = tap - r * 3;
            const int j = l15 + s;                    // patch col
            #pragma unroll
            for (int h = 0; h < 2; ++h) {
                const int c = h * 4 + lh;             // cin group 0..7
                const int sl = c ^ (j & 7);
                f16x8 af[4], bf[4];
                #pragma unroll
                for (int ot = 0; ot < 4; ++ot) {
                    int oc = wc * 64 + ot * 16 + l15;
                    bf[ot] = *reinterpret_cast<const f16x8*>(
                        wB1 + (size_t)(((tap * 8 + c) * 256 + oc)) * 8);
                }
                #pragma unroll
                for (int ty = 0; ty < 4; ++ty) {
                    int row = wr * 4 + ty + r;
                    af[ty] = *reinterpret_cast<const f16x8*>(xs + (row * 18 + j) * 64 + sl * 8);
                }
                #pragma unroll
                for (int ty = 0; ty < 4; ++ty)
                    #pragma unroll
                    for (int ot = 0; ot < 4; ++ot)
                        acc[ty][ot] = __builtin_amdgcn_mfma_f32_16x16x32_f16(
                            af[ty], bf[ot], acc[ty][ot], 0, 0, 0);
            }
        }

        // ---- Phase A epilogue: PHASE 0 -> offsb (LDS); PHASE 1 -> offsT (global) ----
        #pragma unroll
        for (int ot = 0; ot < 4; ++ot) {
            int oc = wc * 64 + ot * 16 + l15;
            if (oc < OCOFFc) {
                float bi = cob[oc];
                bool sig = (oc >= 144);
                int dg, k, comp;
                if (oc < 144) { dg = oc / 18; int rem = oc - dg * 18; k = rem >> 1; comp = rem & 1; }
                else          { int mm = oc - 144; dg = mm / 9; k = mm - dg * 9; comp = 2; }
                int r3 = (dg * 9 + k) * 3 + comp;
                #pragma unroll
                for (int ty = 0; ty < 4; ++ty) {
                    int px = (wr * 4 + ty) * 16 + lh * 4;
                    float v0 = acc[ty][ot][0] + bi, v1 = acc[ty][ot][1] + bi;
                    float v2 = acc[ty][ot][2] + bi, v3 = acc[ty][ot][3] + bi;
                    if (sig) {
                        v0 = 1.f / (1.f + __expf(-v0)); v1 = 1.f / (1.f + __expf(-v1));
                        v2 = 1.f / (1.f + __expf(-v2)); v3 = 1.f / (1.f + __expf(-v3));
                    }
                    __half2 p0 = __halves2half2(__float2half(v0), __float2half(v1));
                    __half2 p1 = __halves2half2(__float2half(v2), __float2half(v3));
                    if constexpr (PHASE == 0) {
                        __half2* d = reinterpret_cast<__half2*>(&offsb[r3 * 130 + px]);
                        d[0] = p0; d[1] = p1;
                    } else {
                        __half2* d = reinterpret_cast<__half2*>(offsTb + r3 * 128 + px);
                        d[0] = p0; d[1] = p1;
                    }
                }
            }
        }
    }
    __syncthreads();   // barrier 2

    if constexpr (PHASE == 1) return;

    // ---- Phase B: wave = image row; dg-pipelined register-staged sampling ----
    const int px = wid * 16 + l15;    // offsb px index
    const int gy = by * 8 + wid;
    const int gx = bx * 16 + l15;

    f32x4 acc2[4];
    const f32x4 zero2 = {0.f, 0.f, 0.f, 0.f};
    #pragma unroll
    for (int n = 0; n < 4; ++n) acc2[n] = zero2;

    float4 gA[12]; float wA[12];
    float4 gB[12]; float wB[12];

    DCN_ISSUE(0, gA, wA);
    #pragma unroll 1
    for (int d = 0; d < 8; d += 2) {
        DCN_ISSUE(d + 1, gB, wB);
        DCN_CONSUME(d, gA, wA);
        if (d + 2 < 8) DCN_ISSUE(d + 2, gA, wA);
        DCN_CONSUME(d + 1, gB, wB);
    }

    // ---- store: D row -> x-offset (lh*4+reg), col -> oc (n*16+l15) ----
    #pragma unroll
    for (int n = 0; n < 4; ++n) {
        int oc = n * 16 + l15;
        float bi = bias[oc];
        float4 v = make_float4(acc2[n][0] + bi, acc2[n][1] + bi,
                               acc2[n][2] + bi, acc2[n][3] + bi);
        *reinterpret_cast<float4*>(
            out + (size_t)(b * 64 + oc) * HWc + gy * 128 + bx * 16 + lh * 4) = v;
    }
}

extern "C" void kernel_launch(void* const* d_in, const int* in_sizes, int n_in,
                              void* d_out, int out_size, void* d_ws, size_t ws_size,
                              hipStream_t stream) {
    const float* x      = (const float*)d_in[0];
    const float* w_off  = (const float*)d_in[1];
    const float* cob    = (const float*)d_in[2];
    const float* weight = (const float*)d_in[3];
    const float* bias   = (const float*)d_in[4];
    float* out = (float*)d_out;
    if (ws_size < WS_NEEDED) return;

    char* ws = (char*)d_ws;
    __half* xT    = (__half*)ws;
    __half* wB1   = (__half*)(ws + WB1_OFF);
    __half* wM    = (__half*)(ws + WM_OFF);
    __half* offsT = (__half*)(ws + OFFST_OFF);

    dim3 grid(8, 16, 2);
    prep_all<<<1825, 256, 0, stream>>>(x, w_off, weight, xT, wB1, wM);
    dcn_fused_k<1><<<grid, 512, 0, stream>>>(xT, wB1, cob, wM, bias, offsT, out);  // A-only diag
    dcn_fused_k<2><<<grid, 512, 0, stream>>>(xT, wB1, cob, wM, bias, offsT, out);  // B-only diag
    dcn_fused_k<0><<<grid, 512, 0, stream>>>(xT, wB1, cob, wM, bias, offsT, out);  // fused (final)
}

// Round 16
// 38.059 us; speedup vs baseline: 1.9407x; 1.9407x over previous
//
#include <hip/hip_runtime.h>
#include <hip/hip_fp16.h>

// DCNv2: B=2, CIN=COUT=64, H=W=128, DG=8, cpg=8, 3x3 s1 p1 d1
constexpr int BB = 2;
constexpr int CINc = 64;
constexpr int HWc = 128 * 128;
constexpr int OCOFFc = 216;   // DG*3*9 offset-conv channels
constexpr int XP = 130;       // padded spatial dim (halo of 1)

// workspace layout (bytes)
constexpr size_t XT_BYTES  = (size_t)BB * 8 * XP * XP * 8 * 2;   // per-(b,dg) planes, 16B/px
constexpr size_t WB1_OFF   = XT_BYTES;
constexpr size_t WB1_BYTES = (size_t)9 * 8 * 256 * 8 * 2;        // offset W [tap][cgrp][oc256][8ci] fp16
constexpr size_t WM_OFF    = WB1_OFF + WB1_BYTES;
constexpr size_t WM_BYTES  = (size_t)8 * 12 * 64 * 8 * 2;        // main W [dg][tap12][oc][8c] fp16
constexpr size_t WS_NEEDED = WM_OFF + WM_BYTES;                  // ~4.7 MB

typedef _Float16 f16x8 __attribute__((ext_vector_type(8)));
typedef float    f32x4 __attribute__((ext_vector_type(4)));

// ---------- K0: fused prep: x->planes, weight transforms, halo zero ----------
__global__ void prep_all(const float* __restrict__ x, const float* __restrict__ w_off,
                         const float* __restrict__ weight,
                         __half* __restrict__ xT, __half* __restrict__ wB1,
                         __half* __restrict__ wM) {
    int bid = blockIdx.x;
    if (bid < 1024) {
        int site = bid * 256 + threadIdx.x;      // B*8*HW = 262144
        int pix = site & (HWc - 1);
        int bdg = site >> 14;
        int dg = bdg & 7, b = bdg >> 3;
        int y = pix >> 7, xc = pix & 127;
        const float* xp = x + (size_t)(b * CINc + dg * 8) * HWc + pix;
        __half2 h0 = __halves2half2(__float2half(xp[0 * HWc]), __float2half(xp[1 * HWc]));
        __half2 h1 = __halves2half2(__float2half(xp[2 * HWc]), __float2half(xp[3 * HWc]));
        __half2 h2 = __halves2half2(__float2half(xp[4 * HWc]), __float2half(xp[5 * HWc]));
        __half2 h3 = __halves2half2(__float2half(xp[6 * HWc]), __float2half(xp[7 * HWc]));
        __half2* o = reinterpret_cast<__half2*>(
            xT + (((size_t)(b * 8 + dg) * XP + y + 1) * XP + xc + 1) * 8);
        o[0] = h0; o[1] = h1; o[2] = h2; o[3] = h3;
        return;
    }
    int idx = (bid - 1024) * 256 + threadIdx.x;
    if (idx < 9 * 8 * 256 * 8) {
        // wB1[tap][cgrp][oc][ci]: fragment-major, coalesced for direct global B-reads
        int ci = idx & 7;
        int oc = (idx >> 3) & 255;
        int c  = (idx >> 11) & 7;
        int tap = idx >> 14;
        float v = (oc < OCOFFc) ? w_off[oc * 576 + (c * 8 + ci) * 9 + tap] : 0.f;
        wB1[idx] = __float2half(v);
    } else if (idx < 9 * 8 * 256 * 8 + 8 * 12 * 64 * 8) {
        int j = idx - 9 * 8 * 256 * 8;       // wM[dg][tap12][oc][c]
        int c = j & 7;
        int oc = (j >> 3) & 63;
        int tg = j >> 9;                      // dg*12 + tap
        int tap = tg % 12;
        int dg = tg / 12;
        float v = (tap < 9) ? weight[oc * 576 + (dg * 8 + c) * 9 + tap] : 0.f;
        wM[j] = __float2half(v);
    } else {
        int j2 = idx - (9 * 8 * 256 * 8 + 8 * 12 * 64 * 8);   // halo zero: 16 planes x 516 px
        if (j2 < 16 * 516) {
            int plane = j2 / 516;
            int p = j2 - plane * 516;
            int y, xx;
            if (p < 130)      { y = 0;           xx = p; }
            else if (p < 260) { y = 129;         xx = p - 130; }
            else if (p < 388) { y = 1 + p - 260; xx = 0; }
            else              { y = 1 + p - 388; xx = 129; }
            uint4 z = {0u, 0u, 0u, 0u};
            *reinterpret_cast<uint4*>(xT + (((size_t)plane * XP + y) * XP + xx) * 8) = z;
        }
    }
}

// Phase B chunk issue: bf loads FIRST (so MFMA's operand is oldest in vmcnt),
// then one ds_read_b64 of (oy,ox,m), addr math, 4 corner gathers.
// D_ runtime, S_ literal 0/1/2; ACT compile-time-ish guard for tail.
#define DCN_IC(D_, S_, BF, G, W, ACT)                                          \
  {                                                                            \
    const int dci_ = (D_);                                                     \
    if (ACT) {                                                                 \
      _Pragma("unroll")                                                        \
      for (int n_ = 0; n_ < 4; ++n_)                                           \
        BF[n_] = *reinterpret_cast<const f16x8*>(                              \
            wM + (size_t)((dci_ * 12 + (S_) * 4 + lh) * 64 + n_ * 16 + l15) * 8); \
      const int kg_ = (S_) * 4 + lh;                                           \
      if ((S_) < 2 || lh == 0) {                                               \
        uint2 ov_ = *reinterpret_cast<const uint2*>(                           \
            offsb + ((size_t)(dci_ * 128 + px)) * 36 + kg_ * 4);               \
        __half2 p0_ = *reinterpret_cast<const __half2*>(&ov_.x);               \
        __half2 p1_ = *reinterpret_cast<const __half2*>(&ov_.y);               \
        float oy_ = __half2float(__low2half(p0_));                             \
        float ox_ = __half2float(__high2half(p0_));                            \
        float mk_ = __half2float(__low2half(p1_));                             \
        const int ki_ = kg_ / 3, kj_ = kg_ - ki_ * 3;                          \
        float sy_ = oy_ + (float)(gy - 1 + ki_);                               \
        float sx_ = ox_ + (float)(gx - 1 + kj_);                               \
        float y0f_ = floorf(sy_), x0f_ = floorf(sx_);                          \
        int iy0_ = (int)y0f_, ix0_ = (int)x0f_;                                \
        float ly_ = sy_ - y0f_, lx_ = sx_ - x0f_;                              \
        float hy_ = 1.f - ly_, hx_ = 1.f - lx_;                                \
        float vy0_ = ((unsigned)iy0_ < 128u) ? 1.f : 0.f;                      \
        float vy1_ = ((unsigned)(iy0_ + 1) < 128u) ? 1.f : 0.f;                \
        float vx0_ = ((unsigned)ix0_ < 128u) ? 1.f : 0.f;                      \
        float vx1_ = ((unsigned)(ix0_ + 1) < 128u) ? 1.f : 0.f;                \
        W[0] = __floats2half2_rn(hy_ * hx_ * vy0_ * vx0_ * mk_,                \
                                 hy_ * lx_ * vy0_ * vx1_ * mk_);               \
        W[1] = __floats2half2_rn(ly_ * hx_ * vy1_ * vx0_ * mk_,                \
                                 ly_ * lx_ * vy1_ * vx1_ * mk_);               \
        int y0c_ = min(max(iy0_, 0), 127), y1c_ = min(max(iy0_ + 1, 0), 127);  \
        int x0c_ = min(max(ix0_, 0), 127), x1c_ = min(max(ix0_ + 1, 0), 127);  \
        const __half* xb_ = xT + (size_t)(b * 8 + dci_) * XP * XP * 8;         \
        G[0] = *reinterpret_cast<const float4*>(xb_ + ((size_t)(y0c_ + 1) * XP + x0c_ + 1) * 8); \
        G[1] = *reinterpret_cast<const float4*>(xb_ + ((size_t)(y0c_ + 1) * XP + x1c_ + 1) * 8); \
        G[2] = *reinterpret_cast<const float4*>(xb_ + ((size_t)(y1c_ + 1) * XP + x0c_ + 1) * 8); \
        G[3] = *reinterpret_cast<const float4*>(xb_ + ((size_t)(y1c_ + 1) * XP + x1c_ + 1) * 8); \
      } else {                                                                 \
        const float4 z4_ = {0.f, 0.f, 0.f, 0.f};                               \
        W[0] = __float2half2_rn(0.f); W[1] = __float2half2_rn(0.f);            \
        G[0] = z4_; G[1] = z4_; G[2] = z4_; G[3] = z4_;                        \
      }                                                                        \
    } else {                                                                   \
      const float4 z4_ = {0.f, 0.f, 0.f, 0.f};                                 \
      const f16x8 zf_ = {0, 0, 0, 0, 0, 0, 0, 0};                              \
      W[0] = __float2half2_rn(0.f); W[1] = __float2half2_rn(0.f);              \
      G[0] = z4_; G[1] = z4_; G[2] = z4_; G[3] = z4_;                          \
      BF[0] = zf_; BF[1] = zf_; BF[2] = zf_; BF[3] = zf_;                      \
    }                                                                          \
  }

// Phase B chunk consume: blend -> af, 4 MFMAs.
// Blend waits on G (older than next chunk's loads); MFMA's BF already resident.
#define DCN_CC(BF, G, W)                                                       \
  {                                                                            \
    __half2 W00_ = __half2half2(__low2half(W[0]));                             \
    __half2 W01_ = __half2half2(__high2half(W[0]));                            \
    __half2 W10_ = __half2half2(__low2half(W[1]));                             \
    __half2 W11_ = __half2half2(__high2half(W[1]));                            \
    const __half2* a00_ = reinterpret_cast<const __half2*>(&G[0]);             \
    const __half2* a01_ = reinterpret_cast<const __half2*>(&G[1]);             \
    const __half2* a10_ = reinterpret_cast<const __half2*>(&G[2]);             \
    const __half2* a11_ = reinterpret_cast<const __half2*>(&G[3]);             \
    __align__(16) __half2 rr_[4];                                              \
    _Pragma("unroll")                                                          \
    for (int cc_ = 0; cc_ < 4; ++cc_)                                          \
      rr_[cc_] = __hfma2(a00_[cc_], W00_,                                      \
                 __hfma2(a01_[cc_], W01_,                                      \
                 __hfma2(a10_[cc_], W10_, __hmul2(a11_[cc_], W11_))));         \
    f16x8 af_ = *reinterpret_cast<const f16x8*>(rr_);                          \
    _Pragma("unroll")                                                          \
    for (int n_ = 0; n_ < 4; ++n_)                                             \
      acc2[n_] = __builtin_amdgcn_mfma_f32_16x16x32_f16(                       \
          af_, BF[n_], acc2[n_], 0, 0, 0);                                     \
  }

// ---------- Fused DCN: 128px tile, 512 thr, grid 256, XCD swizzle ----------
// Phase A: r10 structure (bf direct from global, no weight LDS, no tap barriers).
// Phase B: chunk-granular software pipeline (4 bf + 4 gathers per chunk,
//          ping-pong buffers, bf oldest-first) -> steady 8 loads in flight
//          across every MFMA cluster. offsb packed [dg][px][tap][4] for
//          single-b64 offset reads. 2 barriers total.
__global__ __launch_bounds__(512, 2) void dcn_fused_k(
        const __half* __restrict__ xT, const __half* __restrict__ wB1,
        const float* __restrict__ cob, const __half* __restrict__ wM,
        const float* __restrict__ bias, float* __restrict__ out) {
    __shared__ __half xs[1440 * 8];        // 23040 B: [row10][col18][sl8][8ch]
    __shared__ __half offsb[8 * 128 * 36]; // 73728 B: [dg][px][tap9][4: oy,ox,m,pad]
    const int tid = threadIdx.x;
    // XCD-aware swizzle: each XCD gets 32 consecutive vids = 4 contiguous row-bands
    const int fid = blockIdx.x + (blockIdx.y << 3) + (blockIdx.z << 7);
    const int vid = ((fid & 7) << 5) + (fid >> 3);
    const int bx = vid & 7;               // 0..7   (16 px wide)
    const int by = (vid >> 3) & 15;       // 0..15  (8 px tall)
    const int b  = vid >> 7;

    // ---- Phase A staging: x patch rows by*8..+9, cols bx*16..+17, XOR slot swizzle ----
    #pragma unroll
    for (int it = 0; it < 3; ++it) {
        int idx = tid + it * 512;
        if (idx < 1440) {
            int yl = idx / 144;                  // 144 = 18 cols * 8 slots
            int rem = idx - yl * 144;
            int cl = rem >> 3, sl = rem & 7;
            int dg = sl ^ (cl & 7);
            float4 v = *reinterpret_cast<const float4*>(
                xT + (((size_t)(b * 8 + dg) * XP + by * 8 + yl) * XP + bx * 16 + cl) * 8);
            *reinterpret_cast<float4*>(xs + idx * 8) = v;
        }
    }
    __syncthreads();   // barrier 1: xs ready (read-only hereafter)

    const int lane = tid & 63;
    const int wid = tid >> 6;
    const int l15 = lane & 15, lh = lane >> 4;

    {   // ---- Phase A: 9-tap implicit GEMM, NO barriers; bf direct from global ----
        const int wr = wid & 1;            // px half (4 image rows)
        const int wc = wid >> 1;           // oc quarter (64 of 256)
        f32x4 acc[4][4];
        const f32x4 zero = {0.f, 0.f, 0.f, 0.f};
        #pragma unroll
        for (int ty = 0; ty < 4; ++ty)
            #pragma unroll
            for (int ot = 0; ot < 4; ++ot) acc[ty][ot] = zero;

        #pragma unroll 3
        for (int tap = 0; tap < 9; ++tap) {
            const int r = tap / 3, s = tap - r * 3;
            const int j = l15 + s;                    // patch col
            #pragma unroll
            for (int h = 0; h < 2; ++h) {
                const int c = h * 4 + lh;             // cin group 0..7
                const int sl = c ^ (j & 7);
                f16x8 af[4], bf[4];
                #pragma unroll
                for (int ot = 0; ot < 4; ++ot) {
                    int oc = wc * 64 + ot * 16 + l15;
                    bf[ot] = *reinterpret_cast<const f16x8*>(
                        wB1 + (size_t)(((tap * 8 + c) * 256 + oc)) * 8);
                }
                #pragma unroll
                for (int ty = 0; ty < 4; ++ty) {
                    int row = wr * 4 + ty + r;
                    af[ty] = *reinterpret_cast<const f16x8*>(xs + (row * 18 + j) * 64 + sl * 8);
                }
                #pragma unroll
                for (int ty = 0; ty < 4; ++ty)
                    #pragma unroll
                    for (int ot = 0; ot < 4; ++ot)
                        acc[ty][ot] = __builtin_amdgcn_mfma_f32_16x16x32_f16(
                            af[ty], bf[ot], acc[ty][ot], 0, 0, 0);
            }
        }

        // ---- Phase A epilogue -> offsb[dg][px][k*4+comp] ----
        #pragma unroll
        for (int ot = 0; ot < 4; ++ot) {
            int oc = wc * 64 + ot * 16 + l15;
            if (oc < OCOFFc) {
                float bi = cob[oc];
                bool sig = (oc >= 144);
                int dg, k, comp;
                if (oc < 144) { dg = oc / 18; int rem = oc - dg * 18; k = rem >> 1; comp = rem & 1; }
                else          { int mm = oc - 144; dg = mm / 9; k = mm - dg * 9; comp = 2; }
                #pragma unroll
                for (int ty = 0; ty < 4; ++ty) {
                    int pxw = (wr * 4 + ty) * 16 + lh * 4;
                    float v0 = acc[ty][ot][0] + bi, v1 = acc[ty][ot][1] + bi;
                    float v2 = acc[ty][ot][2] + bi, v3 = acc[ty][ot][3] + bi;
                    if (sig) {
                        v0 = 1.f / (1.f + __expf(-v0)); v1 = 1.f / (1.f + __expf(-v1));
                        v2 = 1.f / (1.f + __expf(-v2)); v3 = 1.f / (1.f + __expf(-v3));
                    }
                    size_t base = (size_t)(dg * 128) * 36 + k * 4 + comp;
                    offsb[base + (size_t)(pxw + 0) * 36] = __float2half(v0);
                    offsb[base + (size_t)(pxw + 1) * 36] = __float2half(v1);
                    offsb[base + (size_t)(pxw + 2) * 36] = __float2half(v2);
                    offsb[base + (size_t)(pxw + 3) * 36] = __float2half(v3);
                }
            }
        }
    }
    __syncthreads();   // barrier 2: offsb complete

    // ---- Phase B: wave = image row; chunk-pipelined (24 chunks = 8 dg x 3 s) ----
    const int px = wid * 16 + l15;    // offsb px index
    const int gy = by * 8 + wid;
    const int gx = bx * 16 + l15;

    f32x4 acc2[4];
    const f32x4 zero2 = {0.f, 0.f, 0.f, 0.f};
    #pragma unroll
    for (int n = 0; n < 4; ++n) acc2[n] = zero2;

    f16x8 bfX[4], bfY[4];
    float4 gX[4], gY[4];
    __half2 wX[2], wY[2];

    DCN_IC(0, 0, bfX, gX, wX, true);
    #pragma unroll 1
    for (int dp = 0; dp < 4; ++dp) {
        const int d0 = dp * 2;
        DCN_IC(d0,     1, bfY, gY, wY, true);     DCN_CC(bfX, gX, wX);   // (d0,0)
        DCN_IC(d0,     2, bfX, gX, wX, true);     DCN_CC(bfY, gY, wY);   // (d0,1)
        DCN_IC(d0 + 1, 0, bfY, gY, wY, true);     DCN_CC(bfX, gX, wX);   // (d0,2)
        DCN_IC(d0 + 1, 1, bfX, gX, wX, true);     DCN_CC(bfY, gY, wY);   // (d0+1,0)
        DCN_IC(d0 + 1, 2, bfY, gY, wY, true);     DCN_CC(bfX, gX, wX);   // (d0+1,1)
        DCN_IC(d0 + 2, 0, bfX, gX, wX, dp < 3);   DCN_CC(bfY, gY, wY);   // (d0+1,2)
    }

    // ---- store: D row -> x-offset (lh*4+reg), col -> oc (n*16+l15) ----
    #pragma unroll
    for (int n = 0; n < 4; ++n) {
        int oc = n * 16 + l15;
        float bi = bias[oc];
        float4 v = make_float4(acc2[n][0] + bi, acc2[n][1] + bi,
                               acc2[n][2] + bi, acc2[n][3] + bi);
        *reinterpret_cast<float4*>(
            out + (size_t)(b * 64 + oc) * HWc + gy * 128 + bx * 16 + lh * 4) = v;
    }
}

extern "C" void kernel_launch(void* const* d_in, const int* in_sizes, int n_in,
                              void* d_out, int out_size, void* d_ws, size_t ws_size,
                              hipStream_t stream) {
    const float* x      = (const float*)d_in[0];
    const float* w_off  = (const float*)d_in[1];
    const float* cob    = (const float*)d_in[2];
    const float* weight = (const float*)d_in[3];
    const float* bias   = (const float*)d_in[4];
    float* out = (float*)d_out;
    if (ws_size < WS_NEEDED) return;

    char* ws = (char*)d_ws;
    __half* xT  = (__half*)ws;
    __half* wB1 = (__half*)(ws + WB1_OFF);
    __half* wM  = (__half*)(ws + WM_OFF);

    prep_all<<<1825, 256, 0, stream>>>(x, w_off, weight, xT, wB1, wM);
    dcn_fused_k<<<dim3(8, 16, 2), 512, 0, stream>>>(xT, wB1, cob, wM, bias, out);
}

// Round 17
// 36.359 us; speedup vs baseline: 2.0314x; 1.0467x over previous
//
#include <hip/hip_runtime.h>
#include <hip/hip_fp16.h>

// DCNv2: B=2, CIN=COUT=64, H=W=128, DG=8, cpg=8, 3x3 s1 p1 d1
constexpr int BB = 2;
constexpr int CINc = 64;
constexpr int HWc = 128 * 128;
constexpr int OCOFFc = 216;   // DG*3*9 offset-conv channels
constexpr int XP = 130;       // padded spatial dim (halo of 1)

// workspace layout (bytes)
constexpr size_t XT_BYTES  = (size_t)BB * 8 * XP * XP * 8 * 2;   // per-(b,dg) planes, 16B/px
constexpr size_t WB1_OFF   = XT_BYTES;
constexpr size_t WB1_BYTES = (size_t)9 * 8 * 256 * 8 * 2;        // offset W [tap][cgrp][oc256][8ci] fp16
constexpr size_t WM_OFF    = WB1_OFF + WB1_BYTES;
constexpr size_t WM_BYTES  = (size_t)8 * 12 * 64 * 8 * 2;        // main W [dg][tap12][oc][8c] fp16
constexpr size_t WS_NEEDED = WM_OFF + WM_BYTES;                  // ~4.7 MB

typedef _Float16 f16x8 __attribute__((ext_vector_type(8)));
typedef float    f32x4 __attribute__((ext_vector_type(4)));

// ---------- K0: fused prep: x->planes, weight transforms, halo zero ----------
__global__ void prep_all(const float* __restrict__ x, const float* __restrict__ w_off,
                         const float* __restrict__ weight,
                         __half* __restrict__ xT, __half* __restrict__ wB1,
                         __half* __restrict__ wM) {
    int bid = blockIdx.x;
    if (bid < 1024) {
        int site = bid * 256 + threadIdx.x;      // B*8*HW = 262144
        int pix = site & (HWc - 1);
        int bdg = site >> 14;
        int dg = bdg & 7, b = bdg >> 3;
        int y = pix >> 7, xc = pix & 127;
        const float* xp = x + (size_t)(b * CINc + dg * 8) * HWc + pix;
        __half2 h0 = __halves2half2(__float2half(xp[0 * HWc]), __float2half(xp[1 * HWc]));
        __half2 h1 = __halves2half2(__float2half(xp[2 * HWc]), __float2half(xp[3 * HWc]));
        __half2 h2 = __halves2half2(__float2half(xp[4 * HWc]), __float2half(xp[5 * HWc]));
        __half2 h3 = __halves2half2(__float2half(xp[6 * HWc]), __float2half(xp[7 * HWc]));
        __half2* o = reinterpret_cast<__half2*>(
            xT + (((size_t)(b * 8 + dg) * XP + y + 1) * XP + xc + 1) * 8);
        o[0] = h0; o[1] = h1; o[2] = h2; o[3] = h3;
        return;
    }
    int idx = (bid - 1024) * 256 + threadIdx.x;
    if (idx < 9 * 8 * 256 * 8) {
        // wB1[tap][cgrp][oc][ci]: fragment-major, coalesced for direct global B-reads
        int ci = idx & 7;
        int oc = (idx >> 3) & 255;
        int c  = (idx >> 11) & 7;
        int tap = idx >> 14;
        float v = (oc < OCOFFc) ? w_off[oc * 576 + (c * 8 + ci) * 9 + tap] : 0.f;
        wB1[idx] = __float2half(v);
    } else if (idx < 9 * 8 * 256 * 8 + 8 * 12 * 64 * 8) {
        int j = idx - 9 * 8 * 256 * 8;       // wM[dg][tap12][oc][c]
        int c = j & 7;
        int oc = (j >> 3) & 63;
        int tg = j >> 9;                      // dg*12 + tap
        int tap = tg % 12;
        int dg = tg / 12;
        float v = (tap < 9) ? weight[oc * 576 + (dg * 8 + c) * 9 + tap] : 0.f;
        wM[j] = __float2half(v);
    } else {
        int j2 = idx - (9 * 8 * 256 * 8 + 8 * 12 * 64 * 8);   // halo zero: 16 planes x 516 px
        if (j2 < 16 * 516) {
            int plane = j2 / 516;
            int p = j2 - plane * 516;
            int y, xx;
            if (p < 130)      { y = 0;           xx = p; }
            else if (p < 260) { y = 129;         xx = p - 130; }
            else if (p < 388) { y = 1 + p - 260; xx = 0; }
            else              { y = 1 + p - 388; xx = 129; }
            uint4 z = {0u, 0u, 0u, 0u};
            *reinterpret_cast<uint4*>(xT + (((size_t)plane * XP + y) * XP + xx) * 8) = z;
        }
    }
}

// Phase B chunk issue: bf loads FIRST (LDS for dg<4 via LDSW, else global),
// then one ds_read_b64 of (oy,ox,m), addr math, 4 corner gathers.
#define DCN_IC(D_, S_, BF, G, W, ACT, LDSW)                                    \
  {                                                                            \
    const int dci_ = (D_);                                                     \
    if (ACT) {                                                                 \
      if (LDSW) {                                                              \
        _Pragma("unroll")                                                      \
        for (int n_ = 0; n_ < 4; ++n_)                                         \
          BF[n_] = *reinterpret_cast<const f16x8*>(                            \
              wMl + ((size_t)((dci_) * 12 + (S_) * 4 + lh) * 64 + n_ * 16 + l15) * 8); \
      } else {                                                                 \
        _Pragma("unroll")                                                      \
        for (int n_ = 0; n_ < 4; ++n_)                                         \
          BF[n_] = *reinterpret_cast<const f16x8*>(                            \
              wM + (size_t)((dci_ * 12 + (S_) * 4 + lh) * 64 + n_ * 16 + l15) * 8); \
      }                                                                        \
      const int kg_ = (S_) * 4 + lh;                                           \
      if ((S_) < 2 || lh == 0) {                                               \
        uint2 ov_ = *reinterpret_cast<const uint2*>(                           \
            offsb + ((size_t)(dci_ * 128 + px)) * 36 + kg_ * 4);               \
        __half2 p0_ = *reinterpret_cast<const __half2*>(&ov_.x);               \
        __half2 p1_ = *reinterpret_cast<const __half2*>(&ov_.y);               \
        float oy_ = __half2float(__low2half(p0_));                             \
        float ox_ = __half2float(__high2half(p0_));                            \
        float mk_ = __half2float(__low2half(p1_));                             \
        const int ki_ = kg_ / 3, kj_ = kg_ - ki_ * 3;                          \
        float sy_ = oy_ + (float)(gy - 1 + ki_);                               \
        float sx_ = ox_ + (float)(gx - 1 + kj_);                               \
        float y0f_ = floorf(sy_), x0f_ = floorf(sx_);                          \
        int iy0_ = (int)y0f_, ix0_ = (int)x0f_;                                \
        float ly_ = sy_ - y0f_, lx_ = sx_ - x0f_;                              \
        float hy_ = 1.f - ly_, hx_ = 1.f - lx_;                                \
        float vy0_ = ((unsigned)iy0_ < 128u) ? 1.f : 0.f;                      \
        float vy1_ = ((unsigned)(iy0_ + 1) < 128u) ? 1.f : 0.f;                \
        float vx0_ = ((unsigned)ix0_ < 128u) ? 1.f : 0.f;                      \
        float vx1_ = ((unsigned)(ix0_ + 1) < 128u) ? 1.f : 0.f;                \
        W[0] = __floats2half2_rn(hy_ * hx_ * vy0_ * vx0_ * mk_,                \
                                 hy_ * lx_ * vy0_ * vx1_ * mk_);               \
        W[1] = __floats2half2_rn(ly_ * hx_ * vy1_ * vx0_ * mk_,                \
                                 ly_ * lx_ * vy1_ * vx1_ * mk_);               \
        int y0c_ = min(max(iy0_, 0), 127), y1c_ = min(max(iy0_ + 1, 0), 127);  \
        int x0c_ = min(max(ix0_, 0), 127), x1c_ = min(max(ix0_ + 1, 0), 127);  \
        const __half* xb_ = xT + (size_t)(b * 8 + dci_) * XP * XP * 8;         \
        G[0] = *reinterpret_cast<const float4*>(xb_ + ((size_t)(y0c_ + 1) * XP + x0c_ + 1) * 8); \
        G[1] = *reinterpret_cast<const float4*>(xb_ + ((size_t)(y0c_ + 1) * XP + x1c_ + 1) * 8); \
        G[2] = *reinterpret_cast<const float4*>(xb_ + ((size_t)(y1c_ + 1) * XP + x0c_ + 1) * 8); \
        G[3] = *reinterpret_cast<const float4*>(xb_ + ((size_t)(y1c_ + 1) * XP + x1c_ + 1) * 8); \
      } else {                                                                 \
        const float4 z4_ = {0.f, 0.f, 0.f, 0.f};                               \
        W[0] = __float2half2_rn(0.f); W[1] = __float2half2_rn(0.f);            \
        G[0] = z4_; G[1] = z4_; G[2] = z4_; G[3] = z4_;                        \
      }                                                                        \
    } else {                                                                   \
      const float4 z4_ = {0.f, 0.f, 0.f, 0.f};                                 \
      const f16x8 zf_ = {0, 0, 0, 0, 0, 0, 0, 0};                              \
      W[0] = __float2half2_rn(0.f); W[1] = __float2half2_rn(0.f);              \
      G[0] = z4_; G[1] = z4_; G[2] = z4_; G[3] = z4_;                          \
      BF[0] = zf_; BF[1] = zf_; BF[2] = zf_; BF[3] = zf_;                      \
    }                                                                          \
  }

// Phase B chunk consume: blend -> af, 4 MFMAs.
#define DCN_CC(BF, G, W)                                                       \
  {                                                                            \
    __half2 W00_ = __half2half2(__low2half(W[0]));                             \
    __half2 W01_ = __half2half2(__high2half(W[0]));                            \
    __half2 W10_ = __half2half2(__low2half(W[1]));                             \
    __half2 W11_ = __half2half2(__high2half(W[1]));                            \
    const __half2* a00_ = reinterpret_cast<const __half2*>(&G[0]);             \
    const __half2* a01_ = reinterpret_cast<const __half2*>(&G[1]);             \
    const __half2* a10_ = reinterpret_cast<const __half2*>(&G[2]);             \
    const __half2* a11_ = reinterpret_cast<const __half2*>(&G[3]);             \
    __align__(16) __half2 rr_[4];                                              \
    _Pragma("unroll")                                                          \
    for (int cc_ = 0; cc_ < 4; ++cc_)                                          \
      rr_[cc_] = __hfma2(a00_[cc_], W00_,                                      \
                 __hfma2(a01_[cc_], W01_,                                      \
                 __hfma2(a10_[cc_], W10_, __hmul2(a11_[cc_], W11_))));         \
    f16x8 af_ = *reinterpret_cast<const f16x8*>(rr_);                          \
    _Pragma("unroll")                                                          \
    for (int n_ = 0; n_ < 4; ++n_)                                             \
      acc2[n_] = __builtin_amdgcn_mfma_f32_16x16x32_f16(                       \
          af_, BF[n_], acc2[n_], 0, 0, 0);                                     \
  }

// ---------- Fused DCN: 128px tile, 512 thr, grid 256, XCD swizzle ----------
// Phase A: r10 structure (bf direct from global, no weight LDS, no tap barriers).
// Phase B: chunk-pipelined; wM for dg 0-3 served from LDS (staged once at kernel
//          start, no extra barriers) to halve the TA line-touch load of bf reads.
__global__ __launch_bounds__(512, 2) void dcn_fused_k(
        const __half* __restrict__ xT, const __half* __restrict__ wB1,
        const float* __restrict__ cob, const __half* __restrict__ wM,
        const float* __restrict__ bias, float* __restrict__ out) {
    __shared__ __half xs[1440 * 8];        // 23040 B: [row10][col18][sl8][8ch]
    __shared__ __half offsb[8 * 128 * 36]; // 73728 B: [dg][px][tap9][4: oy,ox,m,pad]
    __shared__ __half wMl[4 * 12 * 64 * 8];// 49152 B: wM for dg 0-3
    const int tid = threadIdx.x;
    // XCD-aware swizzle: each XCD gets 32 consecutive vids = 4 contiguous row-bands
    const int fid = blockIdx.x + (blockIdx.y << 3) + (blockIdx.z << 7);
    const int vid = ((fid & 7) << 5) + (fid >> 3);
    const int bx = vid & 7;               // 0..7   (16 px wide)
    const int by = (vid >> 3) & 15;       // 0..15  (8 px tall)
    const int b  = vid >> 7;

    // ---- staging: x patch (rows by*8..+9, cols bx*16..+17) + wM dg0-3 -> LDS ----
    #pragma unroll
    for (int it = 0; it < 3; ++it) {
        int idx = tid + it * 512;
        if (idx < 1440) {
            int yl = idx / 144;                  // 144 = 18 cols * 8 slots
            int rem = idx - yl * 144;
            int cl = rem >> 3, sl = rem & 7;
            int dg = sl ^ (cl & 7);
            float4 v = *reinterpret_cast<const float4*>(
                xT + (((size_t)(b * 8 + dg) * XP + by * 8 + yl) * XP + bx * 16 + cl) * 8);
            *reinterpret_cast<float4*>(xs + idx * 8) = v;
        }
    }
    #pragma unroll
    for (int i = 0; i < 6; ++i) {              // 3072 float4 = 48 KB
        int idx = tid + i * 512;
        *reinterpret_cast<float4*>(wMl + (size_t)idx * 8) =
            *reinterpret_cast<const float4*>(wM + (size_t)idx * 8);
    }
    __syncthreads();   // barrier 1: xs + wMl ready (read-only hereafter)

    const int lane = tid & 63;
    const int wid = tid >> 6;
    const int l15 = lane & 15, lh = lane >> 4;

    {   // ---- Phase A: 9-tap implicit GEMM, NO barriers; bf direct from global ----
        const int wr = wid & 1;            // px half (4 image rows)
        const int wc = wid >> 1;           // oc quarter (64 of 256)
        f32x4 acc[4][4];
        const f32x4 zero = {0.f, 0.f, 0.f, 0.f};
        #pragma unroll
        for (int ty = 0; ty < 4; ++ty)
            #pragma unroll
            for (int ot = 0; ot < 4; ++ot) acc[ty][ot] = zero;

        #pragma unroll 3
        for (int tap = 0; tap < 9; ++tap) {
            const int r = tap / 3, s = tap - r * 3;
            const int j = l15 + s;                    // patch col
            #pragma unroll
            for (int h = 0; h < 2; ++h) {
                const int c = h * 4 + lh;             // cin group 0..7
                const int sl = c ^ (j & 7);
                f16x8 af[4], bf[4];
                #pragma unroll
                for (int ot = 0; ot < 4; ++ot) {
                    int oc = wc * 64 + ot * 16 + l15;
                    bf[ot] = *reinterpret_cast<const f16x8*>(
                        wB1 + (size_t)(((tap * 8 + c) * 256 + oc)) * 8);
                }
                #pragma unroll
                for (int ty = 0; ty < 4; ++ty) {
                    int row = wr * 4 + ty + r;
                    af[ty] = *reinterpret_cast<const f16x8*>(xs + (row * 18 + j) * 64 + sl * 8);
                }
                #pragma unroll
                for (int ty = 0; ty < 4; ++ty)
                    #pragma unroll
                    for (int ot = 0; ot < 4; ++ot)
                        acc[ty][ot] = __builtin_amdgcn_mfma_f32_16x16x32_f16(
                            af[ty], bf[ot], acc[ty][ot], 0, 0, 0);
            }
        }

        // ---- Phase A epilogue -> offsb[dg][px][k*4+comp] ----
        #pragma unroll
        for (int ot = 0; ot < 4; ++ot) {
            int oc = wc * 64 + ot * 16 + l15;
            if (oc < OCOFFc) {
                float bi = cob[oc];
                bool sig = (oc >= 144);
                int dg, k, comp;
                if (oc < 144) { dg = oc / 18; int rem = oc - dg * 18; k = rem >> 1; comp = rem & 1; }
                else          { int mm = oc - 144; dg = mm / 9; k = mm - dg * 9; comp = 2; }
                #pragma unroll
                for (int ty = 0; ty < 4; ++ty) {
                    int pxw = (wr * 4 + ty) * 16 + lh * 4;
                    float v0 = acc[ty][ot][0] + bi, v1 = acc[ty][ot][1] + bi;
                    float v2 = acc[ty][ot][2] + bi, v3 = acc[ty][ot][3] + bi;
                    if (sig) {
                        v0 = 1.f / (1.f + __expf(-v0)); v1 = 1.f / (1.f + __expf(-v1));
                        v2 = 1.f / (1.f + __expf(-v2)); v3 = 1.f / (1.f + __expf(-v3));
                    }
                    size_t base = (size_t)(dg * 128) * 36 + k * 4 + comp;
                    offsb[base + (size_t)(pxw + 0) * 36] = __float2half(v0);
                    offsb[base + (size_t)(pxw + 1) * 36] = __float2half(v1);
                    offsb[base + (size_t)(pxw + 2) * 36] = __float2half(v2);
                    offsb[base + (size_t)(pxw + 3) * 36] = __float2half(v3);
                }
            }
        }
    }
    __syncthreads();   // barrier 2: offsb complete

    // ---- Phase B: wave = image row; chunk-pipelined (24 chunks = 8 dg x 3 s) ----
    const int px = wid * 16 + l15;    // offsb px index
    const int gy = by * 8 + wid;
    const int gx = bx * 16 + l15;

    f32x4 acc2[4];
    const f32x4 zero2 = {0.f, 0.f, 0.f, 0.f};
    #pragma unroll
    for (int n = 0; n < 4; ++n) acc2[n] = zero2;

    f16x8 bfX[4], bfY[4];
    float4 gX[4], gY[4];
    __half2 wX[2], wY[2];

    // dg 0-3: bf from LDS (wMl)
    DCN_IC(0, 0, bfX, gX, wX, true, true);
    #pragma unroll 1
    for (int dp = 0; dp < 2; ++dp) {
        const int d0 = dp * 2;
        DCN_IC(d0,     1, bfY, gY, wY, true, true);   DCN_CC(bfX, gX, wX);
        DCN_IC(d0,     2, bfX, gX, wX, true, true);   DCN_CC(bfY, gY, wY);
        DCN_IC(d0 + 1, 0, bfY, gY, wY, true, true);   DCN_CC(bfX, gX, wX);
        DCN_IC(d0 + 1, 1, bfX, gX, wX, true, true);   DCN_CC(bfY, gY, wY);
        DCN_IC(d0 + 1, 2, bfY, gY, wY, true, true);   DCN_CC(bfX, gX, wX);
        if (dp == 0) { DCN_IC(2, 0, bfX, gX, wX, true, true); }
        else         { DCN_IC(4, 0, bfX, gX, wX, true, false); }
        DCN_CC(bfY, gY, wY);
    }
    // dg 4-7: bf from global (wM)
    #pragma unroll 1
    for (int dp = 2; dp < 4; ++dp) {
        const int d0 = dp * 2;
        DCN_IC(d0,     1, bfY, gY, wY, true, false);  DCN_CC(bfX, gX, wX);
        DCN_IC(d0,     2, bfX, gX, wX, true, false);  DCN_CC(bfY, gY, wY);
        DCN_IC(d0 + 1, 0, bfY, gY, wY, true, false);  DCN_CC(bfX, gX, wX);
        DCN_IC(d0 + 1, 1, bfX, gX, wX, true, false);  DCN_CC(bfY, gY, wY);
        DCN_IC(d0 + 1, 2, bfY, gY, wY, true, false);  DCN_CC(bfX, gX, wX);
        DCN_IC(d0 + 2, 0, bfX, gX, wX, dp < 3, false); DCN_CC(bfY, gY, wY);
    }

    // ---- store: D row -> x-offset (lh*4+reg), col -> oc (n*16+l15) ----
    #pragma unroll
    for (int n = 0; n < 4; ++n) {
        int oc = n * 16 + l15;
        float bi = bias[oc];
        float4 v = make_float4(acc2[n][0] + bi, acc2[n][1] + bi,
                               acc2[n][2] + bi, acc2[n][3] + bi);
        *reinterpret_cast<float4*>(
            out + (size_t)(b * 64 + oc) * HWc + gy * 128 + bx * 16 + lh * 4) = v;
    }
}

extern "C" void kernel_launch(void* const* d_in, const int* in_sizes, int n_in,
                              void* d_out, int out_size, void* d_ws, size_t ws_size,
                              hipStream_t stream) {
    const float* x      = (const float*)d_in[0];
    const float* w_off  = (const float*)d_in[1];
    const float* cob    = (const float*)d_in[2];
    const float* weight = (const float*)d_in[3];
    const float* bias   = (const float*)d_in[4];
    float* out = (float*)d_out;
    if (ws_size < WS_NEEDED) return;

    char* ws = (char*)d_ws;
    __half* xT  = (__half*)ws;
    __half* wB1 = (__half*)(ws + WB1_OFF);
    __half* wM  = (__half*)(ws + WM_OFF);

    prep_all<<<1825, 256, 0, stream>>>(x, w_off, weight, xT, wB1, wM);
    dcn_fused_k<<<dim3(8, 16, 2), 512, 0, stream>>>(xT, wB1, cob, wM, bias, out);
}

// Round 18
// 34.038 us; speedup vs baseline: 2.1700x; 1.0682x over previous
//
#include <hip/hip_runtime.h>
#include <hip/hip_fp16.h>

// DCNv2: B=2, CIN=COUT=64, H=W=128, DG=8, cpg=8, 3x3 s1 p1 d1
constexpr int BB = 2;
constexpr int CINc = 64;
constexpr int HWc = 128 * 128;
constexpr int OCOFFc = 216;   // DG*3*9 offset-conv channels
constexpr int XP = 130;       // padded spatial dim (halo of 1)

// workspace layout (bytes)
constexpr size_t XT_BYTES  = (size_t)BB * 8 * XP * XP * 8 * 2;   // per-(b,dg) planes, 16B/px
constexpr size_t WB1_OFF   = XT_BYTES;
constexpr size_t WB1_BYTES = (size_t)9 * 8 * 256 * 8 * 2;        // offset W [tap][cgrp][oc256][8ci] fp16
constexpr size_t WM_OFF    = WB1_OFF + WB1_BYTES;
constexpr size_t WM_BYTES  = (size_t)72 * 64 * 8 * 2;            // main W [slot=dg*9+tap][oc][8c] fp16
constexpr size_t WS_NEEDED = WM_OFF + WM_BYTES;                  // ~4.6 MB

typedef _Float16 f16x8 __attribute__((ext_vector_type(8)));
typedef float    f32x4 __attribute__((ext_vector_type(4)));

// ---------- K0: fused prep: x->planes, weight transforms, halo zero ----------
__global__ void prep_all(const float* __restrict__ x, const float* __restrict__ w_off,
                         const float* __restrict__ weight,
                         __half* __restrict__ xT, __half* __restrict__ wB1,
                         __half* __restrict__ wM2) {
    int bid = blockIdx.x;
    if (bid < 1024) {
        int site = bid * 256 + threadIdx.x;      // B*8*HW = 262144
        int pix = site & (HWc - 1);
        int bdg = site >> 14;
        int dg = bdg & 7, b = bdg >> 3;
        int y = pix >> 7, xc = pix & 127;
        const float* xp = x + (size_t)(b * CINc + dg * 8) * HWc + pix;
        __half2 h0 = __halves2half2(__float2half(xp[0 * HWc]), __float2half(xp[1 * HWc]));
        __half2 h1 = __halves2half2(__float2half(xp[2 * HWc]), __float2half(xp[3 * HWc]));
        __half2 h2 = __halves2half2(__float2half(xp[4 * HWc]), __float2half(xp[5 * HWc]));
        __half2 h3 = __halves2half2(__float2half(xp[6 * HWc]), __float2half(xp[7 * HWc]));
        __half2* o = reinterpret_cast<__half2*>(
            xT + (((size_t)(b * 8 + dg) * XP + y + 1) * XP + xc + 1) * 8);
        o[0] = h0; o[1] = h1; o[2] = h2; o[3] = h3;
        return;
    }
    int idx = (bid - 1024) * 256 + threadIdx.x;
    if (idx < 9 * 8 * 256 * 8) {
        // wB1[tap][cgrp][oc][ci]: fragment-major, coalesced for direct global B-reads
        int ci = idx & 7;
        int oc = (idx >> 3) & 255;
        int c  = (idx >> 11) & 7;
        int tap = idx >> 14;
        float v = (oc < OCOFFc) ? w_off[oc * 576 + (c * 8 + ci) * 9 + tap] : 0.f;
        wB1[idx] = __float2half(v);
    } else if (idx < 9 * 8 * 256 * 8 + 72 * 64 * 8) {
        int j = idx - 9 * 8 * 256 * 8;       // wM2[slot][oc][ci], slot = dg*9+tap
        int ci = j & 7;
        int oc = (j >> 3) & 63;
        int slot = j >> 9;
        int dg = slot / 9;
        int tap = slot - dg * 9;
        wM2[j] = __float2half(weight[oc * 576 + (dg * 8 + ci) * 9 + tap]);
    } else {
        int j2 = idx - (9 * 8 * 256 * 8 + 72 * 64 * 8);   // halo zero: 16 planes x 516 px
        if (j2 < 16 * 516) {
            int plane = j2 / 516;
            int p = j2 - plane * 516;
            int y, xx;
            if (p < 130)      { y = 0;           xx = p; }
            else if (p < 260) { y = 129;         xx = p - 130; }
            else if (p < 388) { y = 1 + p - 260; xx = 0; }
            else              { y = 1 + p - 388; xx = 129; }
            uint4 z = {0u, 0u, 0u, 0u};
            *reinterpret_cast<uint4*>(xT + (((size_t)plane * XP + y) * XP + xx) * 8) = z;
        }
    }
}

// Phase B chunk issue for chunk CC_ (slots CC_*4+lh, all lanes useful):
// bf loads FIRST (LDS for slot<36 via LDSW, else global), then b64 offs read,
// addr math, 4 corner gathers.
#define DCN_IC(CC_, BF, G, W, LDSW)                                            \
  {                                                                            \
    const int slot_ = (CC_) * 4 + lh;                                          \
    if (LDSW) {                                                                \
      _Pragma("unroll")                                                        \
      for (int n_ = 0; n_ < 4; ++n_)                                           \
        BF[n_] = *reinterpret_cast<const f16x8*>(                              \
            wMl + ((size_t)slot_ * 64 + n_ * 16 + l15) * 8);                   \
    } else {                                                                   \
      _Pragma("unroll")                                                        \
      for (int n_ = 0; n_ < 4; ++n_)                                           \
        BF[n_] = *reinterpret_cast<const f16x8*>(                              \
            wM2 + ((size_t)slot_ * 64 + n_ * 16 + l15) * 8);                   \
    }                                                                          \
    const int dgc_ = slot_ / 9;                                                \
    const int tap_ = slot_ - dgc_ * 9;                                         \
    uint2 ov_ = *reinterpret_cast<const uint2*>(                               \
        offsb + ((size_t)(dgc_ * 128 + px)) * 36 + tap_ * 4);                  \
    __half2 p0_ = *reinterpret_cast<const __half2*>(&ov_.x);                   \
    __half2 p1_ = *reinterpret_cast<const __half2*>(&ov_.y);                   \
    float oy_ = __half2float(__low2half(p0_));                                 \
    float ox_ = __half2float(__high2half(p0_));                                \
    float mk_ = __half2float(__low2half(p1_));                                 \
    const int ki_ = tap_ / 3, kj_ = tap_ - ki_ * 3;                            \
    float sy_ = oy_ + (float)(gy - 1 + ki_);                                   \
    float sx_ = ox_ + (float)(gx - 1 + kj_);                                   \
    float y0f_ = floorf(sy_), x0f_ = floorf(sx_);                              \
    int iy0_ = (int)y0f_, ix0_ = (int)x0f_;                                    \
    float ly_ = sy_ - y0f_, lx_ = sx_ - x0f_;                                  \
    float hy_ = 1.f - ly_, hx_ = 1.f - lx_;                                    \
    float vy0_ = ((unsigned)iy0_ < 128u) ? 1.f : 0.f;                          \
    float vy1_ = ((unsigned)(iy0_ + 1) < 128u) ? 1.f : 0.f;                    \
    float vx0_ = ((unsigned)ix0_ < 128u) ? 1.f : 0.f;                          \
    float vx1_ = ((unsigned)(ix0_ + 1) < 128u) ? 1.f : 0.f;                    \
    W[0] = __floats2half2_rn(hy_ * hx_ * vy0_ * vx0_ * mk_,                    \
                             hy_ * lx_ * vy0_ * vx1_ * mk_);                   \
    W[1] = __floats2half2_rn(ly_ * hx_ * vy1_ * vx0_ * mk_,                    \
                             ly_ * lx_ * vy1_ * vx1_ * mk_);                   \
    int y0c_ = min(max(iy0_, 0), 127), y1c_ = min(max(iy0_ + 1, 0), 127);      \
    int x0c_ = min(max(ix0_, 0), 127), x1c_ = min(max(ix0_ + 1, 0), 127);      \
    const __half* xb_ = xT + (size_t)(b * 8 + dgc_) * XP * XP * 8;             \
    G[0] = *reinterpret_cast<const float4*>(xb_ + ((size_t)(y0c_ + 1) * XP + x0c_ + 1) * 8); \
    G[1] = *reinterpret_cast<const float4*>(xb_ + ((size_t)(y0c_ + 1) * XP + x1c_ + 1) * 8); \
    G[2] = *reinterpret_cast<const float4*>(xb_ + ((size_t)(y1c_ + 1) * XP + x0c_ + 1) * 8); \
    G[3] = *reinterpret_cast<const float4*>(xb_ + ((size_t)(y1c_ + 1) * XP + x1c_ + 1) * 8); \
  }

// Phase B chunk consume: blend -> af, 4 MFMAs.
#define DCN_CC(BF, G, W)                                                       \
  {                                                                            \
    __half2 W00_ = __half2half2(__low2half(W[0]));                             \
    __half2 W01_ = __half2half2(__high2half(W[0]));                            \
    __half2 W10_ = __half2half2(__low2half(W[1]));                             \
    __half2 W11_ = __half2half2(__high2half(W[1]));                            \
    const __half2* a00_ = reinterpret_cast<const __half2*>(&G[0]);             \
    const __half2* a01_ = reinterpret_cast<const __half2*>(&G[1]);             \
    const __half2* a10_ = reinterpret_cast<const __half2*>(&G[2]);             \
    const __half2* a11_ = reinterpret_cast<const __half2*>(&G[3]);             \
    __align__(16) __half2 rr_[4];                                              \
    _Pragma("unroll")                                                          \
    for (int cc_ = 0; cc_ < 4; ++cc_)                                          \
      rr_[cc_] = __hfma2(a00_[cc_], W00_,                                      \
                 __hfma2(a01_[cc_], W01_,                                      \
                 __hfma2(a10_[cc_], W10_, __hmul2(a11_[cc_], W11_))));         \
    f16x8 af_ = *reinterpret_cast<const f16x8*>(rr_);                          \
    _Pragma("unroll")                                                          \
    for (int n_ = 0; n_ < 4; ++n_)                                             \
      acc2[n_] = __builtin_amdgcn_mfma_f32_16x16x32_f16(                       \
          af_, BF[n_], acc2[n_], 0, 0, 0);                                     \
  }

// ---------- Fused DCN: 128px tile, 512 thr, grid 256, XCD swizzle ----------
// Phase A: r10 structure (bf direct from global, no weight LDS, no tap barriers).
// Phase B: flattened 72-slot K over (dg,tap) -> 18 chunks, zero padding waste;
//          chunk-pipelined; wM2 slots 0-35 from LDS, 36-71 from global.
__global__ __launch_bounds__(512, 2) void dcn_fused_k(
        const __half* __restrict__ xT, const __half* __restrict__ wB1,
        const float* __restrict__ cob, const __half* __restrict__ wM2,
        const float* __restrict__ bias, float* __restrict__ out) {
    __shared__ __half xs[1440 * 8];        // 23040 B: [row10][col18][sl8][8ch]
    __shared__ __half offsb[8 * 128 * 36]; // 73728 B: [dg][px][tap9][4: oy,ox,m,pad]
    __shared__ __half wMl[36 * 64 * 8];    // 36864 B: wM2 slots 0-35
    const int tid = threadIdx.x;
    // XCD-aware swizzle: each XCD gets 32 consecutive vids = 4 contiguous row-bands
    const int fid = blockIdx.x + (blockIdx.y << 3) + (blockIdx.z << 7);
    const int vid = ((fid & 7) << 5) + (fid >> 3);
    const int bx = vid & 7;               // 0..7   (16 px wide)
    const int by = (vid >> 3) & 15;       // 0..15  (8 px tall)
    const int b  = vid >> 7;

    // ---- staging: x patch (rows by*8..+9, cols bx*16..+17) + wM2 slots 0-35 ----
    #pragma unroll
    for (int it = 0; it < 3; ++it) {
        int idx = tid + it * 512;
        if (idx < 1440) {
            int yl = idx / 144;                  // 144 = 18 cols * 8 slots
            int rem = idx - yl * 144;
            int cl = rem >> 3, sl = rem & 7;
            int dg = sl ^ (cl & 7);
            float4 v = *reinterpret_cast<const float4*>(
                xT + (((size_t)(b * 8 + dg) * XP + by * 8 + yl) * XP + bx * 16 + cl) * 8);
            *reinterpret_cast<float4*>(xs + idx * 8) = v;
        }
    }
    #pragma unroll
    for (int i = 0; i < 5; ++i) {              // 2304 float4 = 36864 B
        int idx = tid + i * 512;
        if (idx < 2304)
            *reinterpret_cast<float4*>(wMl + (size_t)idx * 8) =
                *reinterpret_cast<const float4*>(wM2 + (size_t)idx * 8);
    }
    __syncthreads();   // barrier 1: xs + wMl ready (read-only hereafter)

    const int lane = tid & 63;
    const int wid = tid >> 6;
    const int l15 = lane & 15, lh = lane >> 4;

    {   // ---- Phase A: 9-tap implicit GEMM, NO barriers; bf direct from global ----
        const int wr = wid & 1;            // px half (4 image rows)
        const int wc = wid >> 1;           // oc quarter (64 of 256)
        f32x4 acc[4][4];
        const f32x4 zero = {0.f, 0.f, 0.f, 0.f};
        #pragma unroll
        for (int ty = 0; ty < 4; ++ty)
            #pragma unroll
            for (int ot = 0; ot < 4; ++ot) acc[ty][ot] = zero;

        #pragma unroll 3
        for (int tap = 0; tap < 9; ++tap) {
            const int r = tap / 3, s = tap - r * 3;
            const int j = l15 + s;                    // patch col
            #pragma unroll
            for (int h = 0; h < 2; ++h) {
                const int c = h * 4 + lh;             // cin group 0..7
                const int sl = c ^ (j & 7);
                f16x8 af[4], bf[4];
                #pragma unroll
                for (int ot = 0; ot < 4; ++ot) {
                    int oc = wc * 64 + ot * 16 + l15;
                    bf[ot] = *reinterpret_cast<const f16x8*>(
                        wB1 + (size_t)(((tap * 8 + c) * 256 + oc)) * 8);
                }
                #pragma unroll
                for (int ty = 0; ty < 4; ++ty) {
                    int row = wr * 4 + ty + r;
                    af[ty] = *reinterpret_cast<const f16x8*>(xs + (row * 18 + j) * 64 + sl * 8);
                }
                #pragma unroll
                for (int ty = 0; ty < 4; ++ty)
                    #pragma unroll
                    for (int ot = 0; ot < 4; ++ot)
                        acc[ty][ot] = __builtin_amdgcn_mfma_f32_16x16x32_f16(
                            af[ty], bf[ot], acc[ty][ot], 0, 0, 0);
            }
        }

        // ---- Phase A epilogue -> offsb[dg][px][k*4+comp] ----
        #pragma unroll
        for (int ot = 0; ot < 4; ++ot) {
            int oc = wc * 64 + ot * 16 + l15;
            if (oc < OCOFFc) {
                float bi = cob[oc];
                bool sig = (oc >= 144);
                int dg, k, comp;
                if (oc < 144) { dg = oc / 18; int rem = oc - dg * 18; k = rem >> 1; comp = rem & 1; }
                else          { int mm = oc - 144; dg = mm / 9; k = mm - dg * 9; comp = 2; }
                #pragma unroll
                for (int ty = 0; ty < 4; ++ty) {
                    int pxw = (wr * 4 + ty) * 16 + lh * 4;
                    float v0 = acc[ty][ot][0] + bi, v1 = acc[ty][ot][1] + bi;
                    float v2 = acc[ty][ot][2] + bi, v3 = acc[ty][ot][3] + bi;
                    if (sig) {
                        v0 = 1.f / (1.f + __expf(-v0)); v1 = 1.f / (1.f + __expf(-v1));
                        v2 = 1.f / (1.f + __expf(-v2)); v3 = 1.f / (1.f + __expf(-v3));
                    }
                    size_t base = (size_t)(dg * 128) * 36 + k * 4 + comp;
                    offsb[base + (size_t)(pxw + 0) * 36] = __float2half(v0);
                    offsb[base + (size_t)(pxw + 1) * 36] = __float2half(v1);
                    offsb[base + (size_t)(pxw + 2) * 36] = __float2half(v2);
                    offsb[base + (size_t)(pxw + 3) * 36] = __float2half(v3);
                }
            }
        }
    }
    __syncthreads();   // barrier 2: offsb complete

    // ---- Phase B: wave = image row; 18 flattened chunks, ping-pong pipeline ----
    const int px = wid * 16 + l15;    // offsb px index
    const int gy = by * 8 + wid;
    const int gx = bx * 16 + l15;

    f32x4 acc2[4];
    const f32x4 zero2 = {0.f, 0.f, 0.f, 0.f};
    #pragma unroll
    for (int n = 0; n < 4; ++n) acc2[n] = zero2;

    f16x8 bfX[4], bfY[4];
    float4 gX[4], gY[4];
    __half2 wX[2], wY[2];

    DCN_IC(0,  bfX, gX, wX, true);
    DCN_IC(1,  bfY, gY, wY, true);   DCN_CC(bfX, gX, wX);
    DCN_IC(2,  bfX, gX, wX, true);   DCN_CC(bfY, gY, wY);
    DCN_IC(3,  bfY, gY, wY, true);   DCN_CC(bfX, gX, wX);
    DCN_IC(4,  bfX, gX, wX, true);   DCN_CC(bfY, gY, wY);
    DCN_IC(5,  bfY, gY, wY, true);   DCN_CC(bfX, gX, wX);
    DCN_IC(6,  bfX, gX, wX, true);   DCN_CC(bfY, gY, wY);
    DCN_IC(7,  bfY, gY, wY, true);   DCN_CC(bfX, gX, wX);
    DCN_IC(8,  bfX, gX, wX, true);   DCN_CC(bfY, gY, wY);
    DCN_IC(9,  bfY, gY, wY, false);  DCN_CC(bfX, gX, wX);
    DCN_IC(10, bfX, gX, wX, false);  DCN_CC(bfY, gY, wY);
    DCN_IC(11, bfY, gY, wY, false);  DCN_CC(bfX, gX, wX);
    DCN_IC(12, bfX, gX, wX, false);  DCN_CC(bfY, gY, wY);
    DCN_IC(13, bfY, gY, wY, false);  DCN_CC(bfX, gX, wX);
    DCN_IC(14, bfX, gX, wX, false);  DCN_CC(bfY, gY, wY);
    DCN_IC(15, bfY, gY, wY, false);  DCN_CC(bfX, gX, wX);
    DCN_IC(16, bfX, gX, wX, false);  DCN_CC(bfY, gY, wY);
    DCN_IC(17, bfY, gY, wY, false);  DCN_CC(bfX, gX, wX);
    DCN_CC(bfY, gY, wY);

    // ---- store: D row -> x-offset (lh*4+reg), col -> oc (n*16+l15) ----
    #pragma unroll
    for (int n = 0; n < 4; ++n) {
        int oc = n * 16 + l15;
        float bi = bias[oc];
        float4 v = make_float4(acc2[n][0] + bi, acc2[n][1] + bi,
                               acc2[n][2] + bi, acc2[n][3] + bi);
        *reinterpret_cast<float4*>(
            out + (size_t)(b * 64 + oc) * HWc + gy * 128 + bx * 16 + lh * 4) = v;
    }
}

extern "C" void kernel_launch(void* const* d_in, const int* in_sizes, int n_in,
                              void* d_out, int out_size, void* d_ws, size_t ws_size,
                              hipStream_t stream) {
    const float* x      = (const float*)d_in[0];
    const float* w_off  = (const float*)d_in[1];
    const float* cob    = (const float*)d_in[2];
    const float* weight = (const float*)d_in[3];
    const float* bias   = (const float*)d_in[4];
    float* out = (float*)d_out;
    if (ws_size < WS_NEEDED) return;

    char* ws = (char*)d_ws;
    __half* xT  = (__half*)ws;
    __half* wB1 = (__half*)(ws + WB1_OFF);
    __half* wM2 = (__half*)(ws + WM_OFF);

    prep_all<<<1777, 256, 0, stream>>>(x, w_off, weight, xT, wB1, wM2);
    dcn_fused_k<<<dim3(8, 16, 2), 512, 0, stream>>>(xT, wB1, cob, wM2, bias, out);
}